// Round 9
// baseline (209.084 us; speedup 1.0000x reference)
//
#include <hip/hip_runtime.h>
#include <math.h>

// SparseMOELayer: N=65536 tokens, D=128, E=16 experts, top-3 routing.
// Outputs concat: logits[N*D] | importance_loss[1] | comb[N*E]
//
// R9: INTRA-BLOCK SOFTWARE PIPELINE. R7 (occupancy up, dur worse) + R8
// (split phases each slow) => resident blocks run phases in LOCKSTEP:
// gate-VALU saturates while MFMA idles, then vice versa. Fix: each block
// owns 4 token-tiles (grid 256, all resident at 2 blocks/CU); the expert
// loop of tile t is JAMMED with the gate fp64 dots of tile t+1 (per expert
// iter: B-frag loads -> 2 gate q-iters (~350cyc VALU) -> 8 MFMA -> combine)
// so VALU and MFMA pipes are fed simultaneously (m114 overlap, intra-wave).
// Gate uses 2 fp64 chains/token (was 4): ~1e-16 perturbation, six orders
// below the ~1e-6 min top-k gap (fp32-ref passes vs fp64 gate) -> safe.
// Gate reads x direct-global (R4's proven pattern); topk/comb/Af/MFMA/
// epilogue/store are R6 verbatim per tile. B traffic unchanged.
// Regs ~220 (Af64+Bf32+acc32+logits32+GaHa32+temps) < 256 @ 2 waves/SIMD.
// NOT changed (lessons): launch_bounds (256,2); W fp32 LDS; k_loss separate.
#define NTOK 65536
#define DD   128
#define NE   16
#define NK   3
#define TPB  64                    // tokens per tile
#define TILES 4                    // tiles per block
#define NBLK2 (NTOK / (TPB * TILES))   // 256 blocks

#define OUT_LOSS ((size_t)NTOK * DD)
#define OUT_COMB ((size_t)NTOK * DD + 1)

typedef __bf16 bf16x8 __attribute__((ext_vector_type(8)));
typedef __bf16 bf16x4 __attribute__((ext_vector_type(4)));
typedef float  f32x4  __attribute__((ext_vector_type(4)));

__device__ __forceinline__ double softplus_d(double z) {
    return fmax(z, 0.0) + log1p(exp(-fabs(z)));
}

// ---------------------------------------------------------------------------
// K0: pack We[e][d][f] fp32 -> WeTp bf16, FRAGMENT-MAJOR:
//   WeTp[e][nt][s][lane][j]  (flat: e*16384 + (nt*4+s)*512 + lane*8 + j)
//   holds We[d = s*32 + (lane>>4)*8 + j][f = nt*16 + (lane&15)].
// 64 blocks: (expert e = blk>>2, k-step s = blk&3). Block 0 zeroes imp_g.
// ---------------------------------------------------------------------------
__global__ __launch_bounds__(256) void k_prep(
    const float* __restrict__ We, __bf16* __restrict__ WeTp,
    float* __restrict__ imp_g)
{
    __shared__ __bf16 S[32][DD + 8];
    const int tid = threadIdx.x;
    const int e  = blockIdx.x >> 2;
    const int qd = blockIdx.x & 3;             // == k-step s
    if (blockIdx.x == 0 && tid < NE) imp_g[tid] = 0.f;
    const size_t base = (size_t)e * DD * DD + (size_t)qd * 32 * DD;
    for (int i = tid; i < 32 * DD; i += 256) { // coalesced read, d-quarter
        int dd = i >> 7, f = i & 127;
        S[dd][f] = (__bf16)We[base + i];
    }
    __syncthreads();
    #pragma unroll
    for (int it = 0; it < 2; it++) {
        int lin  = it * 256 + tid;             // 0..511 vectors
        int nt   = lin >> 6;
        int lane = lin & 63;
        int quad = lane >> 4, l15 = lane & 15;
        int f = nt * 16 + l15;
        bf16x8 vv;
        #pragma unroll
        for (int j = 0; j < 8; j++) vv[j] = S[quad * 8 + j][f];
        *(bf16x8*)(WeTp + (size_t)e * 16384 +
                   ((size_t)(nt * 4 + qd) * 64 + lane) * 8) = vv;   // coalesced
    }
}

// ---------------------------------------------------------------------------
// K1: FUSED pipelined kernel. 256 tokens/block in 4 tiles of 64; 4 waves.
// Per tile: topk -> comb/xsb-stage -> Af-hoist -> JAM{expert(t) + gate(t+1)}
// -> bias -> yh 2-phase store. Gate(0) runs unjammed in the prologue.
// LDS ~74K (2 blocks/CU): WgT/WnT 16.9K resident, xsb 17.4K, ga 8.7K,
// beS 8K, combT 4.4K, yh 16.9K, tkw/tke/impS 1.6K.
// MFMA 16x16x32 layouts (m89-verified):
//   A: lane l holds A[m=l&15][k=(l>>4)*8+j]; D: col=l&15, row=(l>>4)*4+reg
// ---------------------------------------------------------------------------
__global__ __launch_bounds__(256, 2) void k_fused(
    const float* __restrict__ x, const float* __restrict__ noise,
    const float* __restrict__ Wg, const float* __restrict__ bg,
    const float* __restrict__ Wn, const float* __restrict__ bn,
    const __bf16* __restrict__ WeTp, const float* __restrict__ be,
    float* __restrict__ out, float* __restrict__ imp_g)
{
    __shared__ float WgT[NE][DD + 4];                                  // 8.4K
    __shared__ float WnT[NE][DD + 4];                                  // 8.4K
    __shared__ __bf16 xsb[TPB][DD + 8];                                // 17.4K
    __shared__ double gaS[TPB][NE + 1];                                // 8.7K
    __shared__ float beS[NE][DD];                                      // 8K
    __shared__ float combT[NE][TPB + 4];                               // 4.4K
    __shared__ float yh[32][DD + 4];                                   // 16.9K
    __shared__ float tkw[TPB][NK];
    __shared__ int   tke[TPB][NK];
    __shared__ float impS[NE];

    const int tid  = threadIdx.x;
    const int lane = tid & 63;
    const int wid  = tid >> 6;             // wave -> cols wid*32..+31
    const int l15  = lane & 15;
    const int quad = lane >> 4;
    const int e16  = tid & 15;             // gate-phase expert id
    const int tl   = tid >> 4;             // gate-phase token lane
    const size_t tok0 = (size_t)blockIdx.x * (TPB * TILES);

    // ---- entry staging: W, be, impS, per-thread gate biases ----
    if (tid < NE) impS[tid] = 0.0f;
    for (int i = tid; i < DD * NE; i += 256) {
        int d = i >> 4, ee = i & 15;
        WgT[ee][d] = Wg[i];
        WnT[ee][d] = Wn[i];
    }
    for (int idx = tid; idx < NE * DD; idx += 256)
        beS[idx >> 7][idx & 127] = be[idx];
    const double bge = (double)bg[e16], bne = (double)bn[e16];
    __syncthreads();

    // ---- prologue: GATE(tile 0), unjammed; x direct from global ----
    {
        double Ga[4][2], Ha[4][2];
        #pragma unroll
        for (int g = 0; g < 4; g++)
            #pragma unroll
            for (int j = 0; j < 2; j++) { Ga[g][j] = 0.0; Ha[g][j] = 0.0; }
        const float* xb[4];
        #pragma unroll
        for (int g = 0; g < 4; g++)
            xb[g] = x + (tok0 + g * 16 + tl) * DD;
        #pragma unroll 2
        for (int q = 0; q < DD / 4; q++) {
            f32x4 wg = *(const f32x4*)&WgT[e16][q * 4];
            f32x4 wn = *(const f32x4*)&WnT[e16][q * 4];
            double wg0 = (double)wg[0], wg1 = (double)wg[1];
            double wg2 = (double)wg[2], wg3 = (double)wg[3];
            double wn0 = (double)wn[0], wn1 = (double)wn[1];
            double wn2 = (double)wn[2], wn3 = (double)wn[3];
            #pragma unroll
            for (int g = 0; g < 4; g++) {
                f32x4 xv = *(const f32x4*)(xb[g] + q * 4);
                double x0 = (double)xv[0], x1 = (double)xv[1];
                double x2 = (double)xv[2], x3 = (double)xv[3];
                Ga[g][0] += x0 * wg0; Ga[g][1] += x1 * wg1;
                Ga[g][0] += x2 * wg2; Ga[g][1] += x3 * wg3;
                Ha[g][0] += x0 * wn0; Ha[g][1] += x1 * wn1;
                Ha[g][0] += x2 * wn2; Ha[g][1] += x3 * wn3;
            }
        }
        #pragma unroll
        for (int g = 0; g < 4; g++) {
            int t = g * 16 + tl;
            double gsum = Ga[g][0] + Ga[g][1];
            double hsum = Ha[g][0] + Ha[g][1];
            double nz = (double)noise[(tok0 + t) * NE + e16];
            gaS[t][e16] = gsum + bge + nz * softplus_d(hsum + bne);
        }
    }
    __syncthreads();

    // ---- tile loop ----
    #pragma unroll 1
    for (int t4 = 0; t4 < TILES; t4++) {
        const size_t n0  = tok0 + (size_t)t4 * TPB;
        const size_t n0n = n0 + TPB;
        const bool  more = (t4 < TILES - 1);

        // ---- topk + softmax (64 threads; proven code) ----
        if (tid < TPB) {
            int t = tid;
            double vk[NK]; int ix[NK];
            unsigned taken = 0;
            for (int k = 0; k < NK; k++) {
                double best = -INFINITY; int bi = 0;
                for (int j = 0; j < NE; j++) {
                    if (!((taken >> j) & 1u)) {
                        double gv = gaS[t][j];
                        if (gv > best) { best = gv; bi = j; }  // strict >
                    }
                }
                taken |= 1u << bi;
                vk[k] = best; ix[k] = bi;
            }
            double e1 = exp(vk[1] - vk[0]);
            double e2 = exp(vk[2] - vk[0]);
            double inv = 1.0 / (1.0 + e1 + e2);
            tke[t][0] = ix[0]; tke[t][1] = ix[1]; tke[t][2] = ix[2];
            tkw[t][0] = (float)inv;
            tkw[t][1] = (float)(e1 * inv);
            tkw[t][2] = (float)(e2 * inv);
        }
        __syncthreads();

        // ---- comb (global + combT), impS, xsb staging ----
        #pragma unroll
        for (int g = 0; g < 4; g++) {
            int t = g * 16 + tl;
            float c = 0.f;
            if (tke[t][0] == e16) c = tkw[t][0];
            if (tke[t][1] == e16) c = tkw[t][1];
            if (tke[t][2] == e16) c = tkw[t][2];
            out[OUT_COMB + (n0 + t) * NE + e16] = c;
            combT[e16][t] = c;
            if (c != 0.f) atomicAdd(&impS[e16], c);
        }
        for (int idx = tid; idx < TPB * DD / 4; idx += 256) {  // x as bf16 (vec)
            int t = idx >> 5, q = idx & 31;
            float4 xv = *(const float4*)(x + (n0 + t) * DD + q * 4);
            bf16x4 bv = { (__bf16)xv.x, (__bf16)xv.y, (__bf16)xv.z, (__bf16)xv.w };
            *(bf16x4*)&xsb[t][q * 4] = bv;
        }
        __syncthreads();

        // ---- Af hoist (R6 verbatim) ----
        bf16x8 Af[4][4];
        #pragma unroll
        for (int a = 0; a < 4; a++)
            #pragma unroll
            for (int s = 0; s < 4; s++)
                Af[a][s] = *(const bf16x8*)&xsb[a * 16 + l15][32 * s + quad * 8];

        // ---- JAM: expert(t4) interleaved with gate(t4+1) ----
        f32x4 logits[4][2];
        #pragma unroll
        for (int a = 0; a < 4; a++) {
            logits[a][0] = (f32x4){0.f, 0.f, 0.f, 0.f};
            logits[a][1] = (f32x4){0.f, 0.f, 0.f, 0.f};
        }
        double Ga[4][2], Ha[4][2];
        #pragma unroll
        for (int g = 0; g < 4; g++)
            #pragma unroll
            for (int j = 0; j < 2; j++) { Ga[g][j] = 0.0; Ha[g][j] = 0.0; }
        const float* xbn[4];
        #pragma unroll
        for (int g = 0; g < 4; g++)
            xbn[g] = x + (n0n + g * 16 + tl) * DD;   // deref guarded by `more`

        #pragma unroll 1
        for (int e = 0; e < NE; e++) {
            // B fragments (single buffer; latency hidden by gate VALU below)
            bf16x8 Bf[2][4];
            {
                const __bf16* b = WeTp + (size_t)e * 16384 + (size_t)lane * 8;
                #pragma unroll
                for (int t2 = 0; t2 < 2; t2++)
                    #pragma unroll
                    for (int s = 0; s < 4; s++)
                        Bf[t2][s] = *(const bf16x8*)(b + ((wid * 2 + t2) * 4 + s) * 512);
            }
            // gate(t4+1): 2 q-iters of fp64 dots (VALU fills MFMA/load shadow)
            if (more) {
                #pragma unroll
                for (int qq = 0; qq < 2; qq++) {
                    int q = 2 * e + qq;
                    f32x4 wg = *(const f32x4*)&WgT[e16][q * 4];
                    f32x4 wn = *(const f32x4*)&WnT[e16][q * 4];
                    double wg0 = (double)wg[0], wg1 = (double)wg[1];
                    double wg2 = (double)wg[2], wg3 = (double)wg[3];
                    double wn0 = (double)wn[0], wn1 = (double)wn[1];
                    double wn2 = (double)wn[2], wn3 = (double)wn[3];
                    #pragma unroll
                    for (int g = 0; g < 4; g++) {
                        f32x4 xv = *(const f32x4*)(xbn[g] + q * 4);
                        double x0 = (double)xv[0], x1 = (double)xv[1];
                        double x2 = (double)xv[2], x3 = (double)xv[3];
                        Ga[g][0] += x0 * wg0; Ga[g][1] += x1 * wg1;
                        Ga[g][0] += x2 * wg2; Ga[g][1] += x3 * wg3;
                        Ha[g][0] += x0 * wn0; Ha[g][1] += x1 * wn1;
                        Ha[g][0] += x2 * wn2; Ha[g][1] += x3 * wn3;
                    }
                }
            }
            // MFMA + combine (R6 verbatim)
            f32x4 acc[4][2];
            #pragma unroll
            for (int a = 0; a < 4; a++) {
                acc[a][0] = (f32x4){0.f, 0.f, 0.f, 0.f};
                acc[a][1] = (f32x4){0.f, 0.f, 0.f, 0.f};
            }
            #pragma unroll
            for (int s = 0; s < 4; s++)
                #pragma unroll
                for (int a = 0; a < 4; a++) {
                    acc[a][0] = __builtin_amdgcn_mfma_f32_16x16x32_bf16(
                        Af[a][s], Bf[0][s], acc[a][0], 0, 0, 0);
                    acc[a][1] = __builtin_amdgcn_mfma_f32_16x16x32_bf16(
                        Af[a][s], Bf[1][s], acc[a][1], 0, 0, 0);
                }
            #pragma unroll
            for (int a = 0; a < 4; a++) {
                f32x4 cv = *(const f32x4*)&combT[e][a * 16 + quad * 4];
                #pragma unroll
                for (int r = 0; r < 4; r++) {
                    logits[a][0][r] = fmaf(cv[r], acc[a][0][r], logits[a][0][r]);
                    logits[a][1][r] = fmaf(cv[r], acc[a][1][r], logits[a][1][r]);
                }
            }
        }

        // ---- gate(t4+1) finalize -> gaS (visible after store barriers) ----
        if (more) {
            #pragma unroll
            for (int g = 0; g < 4; g++) {
                int t = g * 16 + tl;
                double gsum = Ga[g][0] + Ga[g][1];
                double hsum = Ha[g][0] + Ha[g][1];
                double nz = (double)noise[(n0n + t) * NE + e16];
                gaS[t][e16] = gsum + bge + nz * softplus_d(hsum + bne);
            }
        }

        // ---- bias epilogue (R6 verbatim) ----
        const int nA = wid * 32, nB = nA + 16;
        #pragma unroll 4
        for (int e = 0; e < NE; e++) {
            float bA = beS[e][nA + l15];
            float bB = beS[e][nB + l15];
            #pragma unroll
            for (int a = 0; a < 4; a++) {
                f32x4 cv = *(const f32x4*)&combT[e][a * 16 + quad * 4];
                #pragma unroll
                for (int r = 0; r < 4; r++) {
                    logits[a][0][r] = fmaf(cv[r], bA, logits[a][0][r]);
                    logits[a][1][r] = fmaf(cv[r], bB, logits[a][1][r]);
                }
            }
        }

        // ---- yh 2-phase coalesced store (R5/R6 verbatim) ----
        #pragma unroll
        for (int h = 0; h < 2; h++) {
            __syncthreads();
            #pragma unroll
            for (int a2 = 0; a2 < 2; a2++) {
                const int a = h * 2 + a2;
                #pragma unroll
                for (int r = 0; r < 4; r++) {
                    int row = a2 * 16 + quad * 4 + r;   // 0..31 within half
                    yh[row][nA + l15] = logits[a][0][r];
                    yh[row][nB + l15] = logits[a][1][r];
                }
            }
            __syncthreads();
            float4* op4 = (float4*)(out + (n0 + h * 32) * DD);
            for (int idx = tid; idx < 32 * DD / 4; idx += 256) {
                int t = idx >> 5, q = idx & 31;
                op4[idx] = *(const float4*)&yh[t][q * 4];
            }
        }
        // barriers above also publish gaS(t4+1) for next tile's topk
        __syncthreads();
    }

    // ---- importance partials -> global (one atomic set per block) ----
    if (tid < NE) atomicAdd(&imp_g[tid], impS[tid]);
}

// ---------------------------------------------------------------------------
// K2: loss from 16 globally-accumulated importances (atomic sums from k_fused).
// ---------------------------------------------------------------------------
__global__ __launch_bounds__(64) void k_loss(
    const float* __restrict__ imp_g, float* __restrict__ out)
{
    if (threadIdx.x == 0) {
        double mean = 0.0;
        for (int i = 0; i < NE; i++) mean += (double)imp_g[i];
        mean /= NE;
        double var = 0.0;
        for (int i = 0; i < NE; i++) {
            double d = (double)imp_g[i] - mean; var += d * d;
        }
        var /= (NE - 1);                    // ddof=1
        out[OUT_LOSS] = (float)(var / (mean * mean));
    }
}

// ---------------------------------------------------------------------------
extern "C" void kernel_launch(void* const* d_in, const int* in_sizes, int n_in,
                              void* d_out, int out_size, void* d_ws, size_t ws_size,
                              hipStream_t stream)
{
    (void)in_sizes; (void)n_in; (void)out_size; (void)ws_size;
    const float* x     = (const float*)d_in[0];
    const float* noise = (const float*)d_in[1];
    const float* Wg    = (const float*)d_in[2];
    const float* bg    = (const float*)d_in[3];
    const float* Wn    = (const float*)d_in[4];
    const float* bn    = (const float*)d_in[5];
    const float* We    = (const float*)d_in[6];
    const float* be    = (const float*)d_in[7];
    float* out = (float*)d_out;

    char*   ws    = (char*)d_ws;
    float*  imp_g = (float*)ws;                  // 64 B (16 floats)
    __bf16* WeTp  = (__bf16*)(ws + 1024);        // 512 KB, 16B-aligned

    hipLaunchKernelGGL(k_prep, dim3(64), dim3(256), 0, stream,
                       We, WeTp, imp_g);
    hipLaunchKernelGGL(k_fused, dim3(NBLK2), dim3(256), 0, stream,
                       x, noise, Wg, bg, Wn, bn, WeTp, be, out, imp_g);
    hipLaunchKernelGGL(k_loss, dim3(1), dim3(64), 0, stream, imp_g, out);
}

// Round 10
// 167.127 us; speedup vs baseline: 1.2510x; 1.2510x over previous
//
#include <hip/hip_runtime.h>
#include <math.h>

// SparseMOELayer: N=65536 tokens, D=128, E=16 experts, top-3 routing.
// Outputs concat: logits[N*D] | importance_loss[1] | comb[N*E]
//
// R10: JAM, CORRECTED. R9's jam test was confounded: grid 256 = 1 block/CU
// (parallelism halved) and jammed gate read x from GLOBAL (memory-latency-
// bound filler). Fix: TILES=2, grid 512 = 2 blocks/CU (8 waves/CU, same as
// R6 best); jammed gate(t+1) reads x from LDS (xs(t+1) staged into the
// SAME xs buffer after tile t's Af-hoist frees it). Per expert iter:
// 8 B-loads -> 2 gate q-iters (~400cyc LDS-fed fp64 VALU covers ~300cyc
// B L2 latency) -> 16 MFMA -> combine => intra-wave MFMA||VALU mix (m114).
// To fit 2 blocks/CU, yh store-staging dropped: epilogue stores D-frags
// direct (4x64B segments per instr, quarter-coalesced, fire-and-forget).
// LDS 71.8K x2 = 143.6K <= 160K. Regs ~222 < 256 @ 2 waves/SIMD.
// Gate 2-chain fp64 order: R9-verified correct. Everything else R6.
// NOT changed (lessons R1/R3/R5/R7/R8): launch_bounds (256,2); W fp32 in
// LDS; k_loss separate; no kernel split; no forced occupancy.
#define NTOK 65536
#define DD   128
#define NE   16
#define NK   3
#define TPB  64                    // tokens per tile
#define TILES 2                    // tiles per block
#define NBLK2 (NTOK / (TPB * TILES))   // 512 blocks = 2/CU

#define OUT_LOSS ((size_t)NTOK * DD)
#define OUT_COMB ((size_t)NTOK * DD + 1)

typedef __bf16 bf16x8 __attribute__((ext_vector_type(8)));
typedef float  f32x4  __attribute__((ext_vector_type(4)));

__device__ __forceinline__ double softplus_d(double z) {
    return fmax(z, 0.0) + log1p(exp(-fabs(z)));
}

// ---------------------------------------------------------------------------
// K0: pack We[e][d][f] fp32 -> WeTp bf16, FRAGMENT-MAJOR:
//   WeTp[e][nt][s][lane][j]  (flat: e*16384 + (nt*4+s)*512 + lane*8 + j)
//   holds We[d = s*32 + (lane>>4)*8 + j][f = nt*16 + (lane&15)].
// 64 blocks: (expert e = blk>>2, k-step s = blk&3). Block 0 zeroes imp_g.
// ---------------------------------------------------------------------------
__global__ __launch_bounds__(256) void k_prep(
    const float* __restrict__ We, __bf16* __restrict__ WeTp,
    float* __restrict__ imp_g)
{
    __shared__ __bf16 S[32][DD + 8];
    const int tid = threadIdx.x;
    const int e  = blockIdx.x >> 2;
    const int qd = blockIdx.x & 3;             // == k-step s
    if (blockIdx.x == 0 && tid < NE) imp_g[tid] = 0.f;
    const size_t base = (size_t)e * DD * DD + (size_t)qd * 32 * DD;
    for (int i = tid; i < 32 * DD; i += 256) { // coalesced read, d-quarter
        int dd = i >> 7, f = i & 127;
        S[dd][f] = (__bf16)We[base + i];
    }
    __syncthreads();
    #pragma unroll
    for (int it = 0; it < 2; it++) {
        int lin  = it * 256 + tid;             // 0..511 vectors
        int nt   = lin >> 6;
        int lane = lin & 63;
        int quad = lane >> 4, l15 = lane & 15;
        int f = nt * 16 + l15;
        bf16x8 vv;
        #pragma unroll
        for (int j = 0; j < 8; j++) vv[j] = S[quad * 8 + j][f];
        *(bf16x8*)(WeTp + (size_t)e * 16384 +
                   ((size_t)(nt * 4 + qd) * 64 + lane) * 8) = vv;   // coalesced
    }
}

// ---------------------------------------------------------------------------
// K1: FUSED pipelined kernel. 128 tokens/block in 2 tiles of 64; 4 waves.
// Entry: stage W, be, xs(tile0). Prologue: gate(t0) from LDS (2-chain).
// Per tile t: topk -> comb/combT -> Af-hoist (xs(t) dead) -> stage xs(t+1)
// -> JAM{expert(t) + gate(t+1) from LDS} -> finalize gaS(t+1) -> bias ->
// direct global stores.
// LDS 71.8K (2 blocks/CU): WgT/WnT 16.9K, xs 33.8K (single buffer,
// time-shared across tiles), gaS 8.7K, combT 4.4K, beS 8K, misc 1.6K.
// MFMA 16x16x32 layouts (m89-verified):
//   A: lane l holds A[m=l&15][k=(l>>4)*8+j]; D: col=l&15, row=(l>>4)*4+reg
// ---------------------------------------------------------------------------
__global__ __launch_bounds__(256, 2) void k_fused(
    const float* __restrict__ x, const float* __restrict__ noise,
    const float* __restrict__ Wg, const float* __restrict__ bg,
    const float* __restrict__ Wn, const float* __restrict__ bn,
    const __bf16* __restrict__ WeTp, const float* __restrict__ be,
    float* __restrict__ out, float* __restrict__ imp_g)
{
    __shared__ float WgT[NE][DD + 4];                                  // 8.4K
    __shared__ float WnT[NE][DD + 4];                                  // 8.4K
    __shared__ float xs[TPB][DD + 4];                                  // 33.8K
    __shared__ double gaS[TPB][NE + 1];                                // 8.7K
    __shared__ float combT[NE][TPB + 4];                               // 4.4K
    __shared__ float beS[NE][DD];                                      // 8K
    __shared__ float tkw[TPB][NK];
    __shared__ int   tke[TPB][NK];
    __shared__ float impS[NE];

    const int tid  = threadIdx.x;
    const int lane = tid & 63;
    const int wid  = tid >> 6;             // wave -> cols wid*32..+31
    const int l15  = lane & 15;
    const int quad = lane >> 4;
    const int e16  = tid & 15;             // gate-phase expert id
    const int tl   = tid >> 4;             // gate-phase token lane
    const size_t tok0 = (size_t)blockIdx.x * (TPB * TILES);

    // ---- entry staging: W, be, xs(tile0); zero impS ----
    if (tid < NE) impS[tid] = 0.0f;
    for (int i = tid; i < DD * NE; i += 256) {
        int d = i >> 4, ee = i & 15;
        WgT[ee][d] = Wg[i];
        WnT[ee][d] = Wn[i];
    }
    for (int idx = tid; idx < NE * DD; idx += 256)
        beS[idx >> 7][idx & 127] = be[idx];
    for (int idx = tid; idx < TPB * DD / 4; idx += 256) {   // coalesced float4
        int t = idx >> 5, q = idx & 31;
        *(f32x4*)&xs[t][q * 4] =
            *(const f32x4*)(x + (tok0 + t) * DD + q * 4);
    }
    const double bge = (double)bg[e16], bne = (double)bn[e16];
    __syncthreads();

    // ---- prologue: GATE(tile 0) from LDS, 2-chain (R9-verified order) ----
    {
        double Ga[4][2], Ha[4][2];
        #pragma unroll
        for (int g = 0; g < 4; g++)
            #pragma unroll
            for (int j = 0; j < 2; j++) { Ga[g][j] = 0.0; Ha[g][j] = 0.0; }
        #pragma unroll 2
        for (int q = 0; q < DD / 4; q++) {
            f32x4 wg = *(const f32x4*)&WgT[e16][q * 4];
            f32x4 wn = *(const f32x4*)&WnT[e16][q * 4];
            double wg0 = (double)wg[0], wg1 = (double)wg[1];
            double wg2 = (double)wg[2], wg3 = (double)wg[3];
            double wn0 = (double)wn[0], wn1 = (double)wn[1];
            double wn2 = (double)wn[2], wn3 = (double)wn[3];
            #pragma unroll
            for (int g = 0; g < 4; g++) {
                f32x4 xv = *(const f32x4*)&xs[g * 16 + tl][q * 4];
                double x0 = (double)xv[0], x1 = (double)xv[1];
                double x2 = (double)xv[2], x3 = (double)xv[3];
                Ga[g][0] += x0 * wg0; Ga[g][1] += x1 * wg1;
                Ga[g][0] += x2 * wg2; Ga[g][1] += x3 * wg3;
                Ha[g][0] += x0 * wn0; Ha[g][1] += x1 * wn1;
                Ha[g][0] += x2 * wn2; Ha[g][1] += x3 * wn3;
            }
        }
        #pragma unroll
        for (int g = 0; g < 4; g++) {
            int t = g * 16 + tl;
            double nz = (double)noise[(tok0 + t) * NE + e16];
            gaS[t][e16] = (Ga[g][0] + Ga[g][1]) + bge
                        + nz * softplus_d((Ha[g][0] + Ha[g][1]) + bne);
        }
    }
    __syncthreads();

    // ---- tile loop ----
    #pragma unroll 1
    for (int t2 = 0; t2 < TILES; t2++) {
        const size_t n0  = tok0 + (size_t)t2 * TPB;
        const size_t n0n = n0 + TPB;
        const bool  more = (t2 < TILES - 1);

        // ---- topk + softmax (64 threads; proven code) ----
        if (tid < TPB) {
            int t = tid;
            double vk[NK]; int ix[NK];
            unsigned taken = 0;
            for (int k = 0; k < NK; k++) {
                double best = -INFINITY; int bi = 0;
                for (int j = 0; j < NE; j++) {
                    if (!((taken >> j) & 1u)) {
                        double gv = gaS[t][j];
                        if (gv > best) { best = gv; bi = j; }  // strict >
                    }
                }
                taken |= 1u << bi;
                vk[k] = best; ix[k] = bi;
            }
            double e1 = exp(vk[1] - vk[0]);
            double e2 = exp(vk[2] - vk[0]);
            double inv = 1.0 / (1.0 + e1 + e2);
            tke[t][0] = ix[0]; tke[t][1] = ix[1]; tke[t][2] = ix[2];
            tkw[t][0] = (float)inv;
            tkw[t][1] = (float)(e1 * inv);
            tkw[t][2] = (float)(e2 * inv);
        }
        __syncthreads();

        // ---- comb (global + combT), impS ----
        #pragma unroll
        for (int g = 0; g < 4; g++) {
            int t = g * 16 + tl;
            float c = 0.f;
            if (tke[t][0] == e16) c = tkw[t][0];
            if (tke[t][1] == e16) c = tkw[t][1];
            if (tke[t][2] == e16) c = tkw[t][2];
            out[OUT_COMB + (n0 + t) * NE + e16] = c;
            combT[e16][t] = c;
            if (c != 0.f) atomicAdd(&impS[e16], c);
        }

        // ---- Af hoist from fp32 xs (R6-verified converts) ----
        bf16x8 Af[4][4];
        #pragma unroll
        for (int a = 0; a < 4; a++)
            #pragma unroll
            for (int s = 0; s < 4; s++) {
                const float* src = &xs[a * 16 + l15][32 * s + quad * 8];
                f32x4 lo = *(const f32x4*)src;
                f32x4 hi = *(const f32x4*)(src + 4);
                bf16x8 vv;
                vv[0] = (__bf16)lo[0]; vv[1] = (__bf16)lo[1];
                vv[2] = (__bf16)lo[2]; vv[3] = (__bf16)lo[3];
                vv[4] = (__bf16)hi[0]; vv[5] = (__bf16)hi[1];
                vv[6] = (__bf16)hi[2]; vv[7] = (__bf16)hi[3];
                Af[a][s] = vv;
            }
        __syncthreads();   // combT ready; ALL xs(t2) reads done

        // ---- stage xs(t2+1) into the freed xs buffer ----
        if (more) {
            for (int idx = tid; idx < TPB * DD / 4; idx += 256) {
                int t = idx >> 5, q = idx & 31;
                *(f32x4*)&xs[t][q * 4] =
                    *(const f32x4*)(x + (n0n + t) * DD + q * 4);
            }
        }
        __syncthreads();   // xs(t2+1) ready for the jammed gate

        // ---- JAM: expert(t2) interleaved with gate(t2+1) from LDS ----
        f32x4 logits[4][2];
        #pragma unroll
        for (int a = 0; a < 4; a++) {
            logits[a][0] = (f32x4){0.f, 0.f, 0.f, 0.f};
            logits[a][1] = (f32x4){0.f, 0.f, 0.f, 0.f};
        }
        double Ga[4][2], Ha[4][2];
        #pragma unroll
        for (int g = 0; g < 4; g++)
            #pragma unroll
            for (int j = 0; j < 2; j++) { Ga[g][j] = 0.0; Ha[g][j] = 0.0; }

        #pragma unroll 1
        for (int e = 0; e < NE; e++) {
            // B fragments (single buffer; L2 latency covered by gate VALU)
            bf16x8 Bf[2][4];
            {
                const __bf16* b = WeTp + (size_t)e * 16384 + (size_t)lane * 8;
                #pragma unroll
                for (int t2b = 0; t2b < 2; t2b++)
                    #pragma unroll
                    for (int s = 0; s < 4; s++)
                        Bf[t2b][s] = *(const bf16x8*)(b + ((wid * 2 + t2b) * 4 + s) * 512);
            }
            // gate(t2+1): 2 q-iters of LDS-fed fp64 dots (fills load shadow)
            if (more) {
                #pragma unroll
                for (int qq = 0; qq < 2; qq++) {
                    int q = 2 * e + qq;
                    f32x4 wg = *(const f32x4*)&WgT[e16][q * 4];
                    f32x4 wn = *(const f32x4*)&WnT[e16][q * 4];
                    double wg0 = (double)wg[0], wg1 = (double)wg[1];
                    double wg2 = (double)wg[2], wg3 = (double)wg[3];
                    double wn0 = (double)wn[0], wn1 = (double)wn[1];
                    double wn2 = (double)wn[2], wn3 = (double)wn[3];
                    #pragma unroll
                    for (int g = 0; g < 4; g++) {
                        f32x4 xv = *(const f32x4*)&xs[g * 16 + tl][q * 4];
                        double x0 = (double)xv[0], x1 = (double)xv[1];
                        double x2 = (double)xv[2], x3 = (double)xv[3];
                        Ga[g][0] += x0 * wg0; Ga[g][1] += x1 * wg1;
                        Ga[g][0] += x2 * wg2; Ga[g][1] += x3 * wg3;
                        Ha[g][0] += x0 * wn0; Ha[g][1] += x1 * wn1;
                        Ha[g][0] += x2 * wn2; Ha[g][1] += x3 * wn3;
                    }
                }
            }
            // MFMA + combine (R6 verbatim)
            f32x4 acc[4][2];
            #pragma unroll
            for (int a = 0; a < 4; a++) {
                acc[a][0] = (f32x4){0.f, 0.f, 0.f, 0.f};
                acc[a][1] = (f32x4){0.f, 0.f, 0.f, 0.f};
            }
            #pragma unroll
            for (int s = 0; s < 4; s++)
                #pragma unroll
                for (int a = 0; a < 4; a++) {
                    acc[a][0] = __builtin_amdgcn_mfma_f32_16x16x32_bf16(
                        Af[a][s], Bf[0][s], acc[a][0], 0, 0, 0);
                    acc[a][1] = __builtin_amdgcn_mfma_f32_16x16x32_bf16(
                        Af[a][s], Bf[1][s], acc[a][1], 0, 0, 0);
                }
            #pragma unroll
            for (int a = 0; a < 4; a++) {
                f32x4 cv = *(const f32x4*)&combT[e][a * 16 + quad * 4];
                #pragma unroll
                for (int r = 0; r < 4; r++) {
                    logits[a][0][r] = fmaf(cv[r], acc[a][0][r], logits[a][0][r]);
                    logits[a][1][r] = fmaf(cv[r], acc[a][1][r], logits[a][1][r]);
                }
            }
        }

        // ---- gate(t2+1) finalize -> gaS ----
        if (more) {
            #pragma unroll
            for (int g = 0; g < 4; g++) {
                int t = g * 16 + tl;
                double nz = (double)noise[(n0n + t) * NE + e16];
                gaS[t][e16] = (Ga[g][0] + Ga[g][1]) + bge
                            + nz * softplus_d((Ha[g][0] + Ha[g][1]) + bne);
            }
        }

        // ---- bias epilogue (R6 verbatim) + DIRECT global stores ----
        const int nA = wid * 32, nB = nA + 16;
        #pragma unroll 4
        for (int e = 0; e < NE; e++) {
            float bA = beS[e][nA + l15];
            float bB = beS[e][nB + l15];
            #pragma unroll
            for (int a = 0; a < 4; a++) {
                f32x4 cv = *(const f32x4*)&combT[e][a * 16 + quad * 4];
                #pragma unroll
                for (int r = 0; r < 4; r++) {
                    logits[a][0][r] = fmaf(cv[r], bA, logits[a][0][r]);
                    logits[a][1][r] = fmaf(cv[r], bB, logits[a][1][r]);
                }
            }
        }
        {
            float* ob = out + n0 * DD;
            #pragma unroll
            for (int a = 0; a < 4; a++)
                #pragma unroll
                for (int r = 0; r < 4; r++) {
                    int row = a * 16 + quad * 4 + r;
                    ob[row * DD + nA + l15] = logits[a][0][r];  // 4x64B segs/instr
                    ob[row * DD + nB + l15] = logits[a][1][r];
                }
        }
        __syncthreads();   // publish gaS(t2+1); protect combT for next tile
    }

    // ---- importance partials -> global (one atomic set per block) ----
    if (tid < NE) atomicAdd(&imp_g[tid], impS[tid]);
}

// ---------------------------------------------------------------------------
// K2: loss from 16 globally-accumulated importances (atomic sums from k_fused).
// ---------------------------------------------------------------------------
__global__ __launch_bounds__(64) void k_loss(
    const float* __restrict__ imp_g, float* __restrict__ out)
{
    if (threadIdx.x == 0) {
        double mean = 0.0;
        for (int i = 0; i < NE; i++) mean += (double)imp_g[i];
        mean /= NE;
        double var = 0.0;
        for (int i = 0; i < NE; i++) {
            double d = (double)imp_g[i] - mean; var += d * d;
        }
        var /= (NE - 1);                    // ddof=1
        out[OUT_LOSS] = (float)(var / (mean * mean));
    }
}

// ---------------------------------------------------------------------------
extern "C" void kernel_launch(void* const* d_in, const int* in_sizes, int n_in,
                              void* d_out, int out_size, void* d_ws, size_t ws_size,
                              hipStream_t stream)
{
    (void)in_sizes; (void)n_in; (void)out_size; (void)ws_size;
    const float* x     = (const float*)d_in[0];
    const float* noise = (const float*)d_in[1];
    const float* Wg    = (const float*)d_in[2];
    const float* bg    = (const float*)d_in[3];
    const float* Wn    = (const float*)d_in[4];
    const float* bn    = (const float*)d_in[5];
    const float* We    = (const float*)d_in[6];
    const float* be    = (const float*)d_in[7];
    float* out = (float*)d_out;

    char*   ws    = (char*)d_ws;
    float*  imp_g = (float*)ws;                  // 64 B (16 floats)
    __bf16* WeTp  = (__bf16*)(ws + 1024);        // 512 KB, 16B-aligned

    hipLaunchKernelGGL(k_prep, dim3(64), dim3(256), 0, stream,
                       We, WeTp, imp_g);
    hipLaunchKernelGGL(k_fused, dim3(NBLK2), dim3(256), 0, stream,
                       x, noise, Wg, bg, Wn, bn, WeTp, be, out, imp_g);
    hipLaunchKernelGGL(k_loss, dim3(1), dim3(64), 0, stream, imp_g, out);
}

// Round 11
// 156.504 us; speedup vs baseline: 1.3360x; 1.0679x over previous
//
#include <hip/hip_runtime.h>
#include <math.h>

// SparseMOELayer: N=65536 tokens, D=128, E=16 experts, top-3 routing.
// Outputs concat: logits[N*D] | importance_loss[1] | comb[N*E]
//
// R11 = R6 verbatim (the measured optimum: k_fused ~75us, e2e ~156us).
// Falsification record (all measured on MI355X):
//  R1:  __launch_bounds__(256,4) -> unified VGPR+AGPR cap 128 < ~190 need
//       -> 1GB scratch spill. NEVER pin 4 waves/EU with this reg budget.
//  R3:  fp64 W in LDS -> G2 LDS-BW-bound; per-block __threadfence ticket
//       -> L2 drain stalls. Both reverted.
//  R5:  LDS 52.7K->35.9K: occupancy flat 19% -> LDS not binding.
//  R7:  512-thr reg-diet: occ 19->39%, dur WORSE -> not wave-starved.
//  R8:  gate/expert kernel split: phases serialize globally -> worse.
//  R9/R10: gate(t+1)-under-expert(t) jam (2 variants): neutral-to-worse;
//       direct (non-LDS-staged) stores cost +21MB write amplification.
//  => The LDS-staged coalesced store and the R6 phase structure are
//       load-bearing. Remaining headroom (<40% pipes) requires ISA-level
//       scheduling not reachable from HIP source.
// Structure: x staged ONCE fp32 (G2 gate reads LDS; X2 builds bf16 Af
// in-register); q-outer W-hoisted fp64 gate (R0 chain order, bit-identical
// top-k); 64-thread top-3; comb -> out + LDS; register-resident dbuf
// expert MFMA loop over packed-coalesced WeTp; bias epilogue; two-half
// LDS-staged float4 store.
#define NTOK 65536
#define DD   128
#define NE   16
#define NK   3
#define TPB  64                    // tokens per block
#define NBLK (NTOK / TPB)          // 1024

#define OUT_LOSS ((size_t)NTOK * DD)
#define OUT_COMB ((size_t)NTOK * DD + 1)

typedef __bf16 bf16x8 __attribute__((ext_vector_type(8)));
typedef float  f32x4  __attribute__((ext_vector_type(4)));

__device__ __forceinline__ double softplus_d(double z) {
    return fmax(z, 0.0) + log1p(exp(-fabs(z)));
}

// ---------------------------------------------------------------------------
// K0: pack We[e][d][f] fp32 -> WeTp bf16, FRAGMENT-MAJOR:
//   WeTp[e][nt][s][lane][j]  (flat: e*16384 + (nt*4+s)*512 + lane*8 + j)
//   holds We[d = s*32 + (lane>>4)*8 + j][f = nt*16 + (lane&15)].
// Consumer loadBp then reads one bf16x8/lane at consecutive 16B -> each
// B-frag load is ONE coalesced 1KB transaction.
// 64 blocks: (expert e = blk>>2, k-step s = blk&3). Block 0 zeroes imp_g.
// ---------------------------------------------------------------------------
__global__ __launch_bounds__(256) void k_prep(
    const float* __restrict__ We, __bf16* __restrict__ WeTp,
    float* __restrict__ imp_g)
{
    __shared__ __bf16 S[32][DD + 8];
    const int tid = threadIdx.x;
    const int e  = blockIdx.x >> 2;
    const int qd = blockIdx.x & 3;             // == k-step s
    if (blockIdx.x == 0 && tid < NE) imp_g[tid] = 0.f;
    const size_t base = (size_t)e * DD * DD + (size_t)qd * 32 * DD;
    for (int i = tid; i < 32 * DD; i += 256) { // coalesced read, d-quarter
        int dd = i >> 7, f = i & 127;
        S[dd][f] = (__bf16)We[base + i];
    }
    __syncthreads();
    #pragma unroll
    for (int it = 0; it < 2; it++) {
        int lin  = it * 256 + tid;             // 0..511 vectors
        int nt   = lin >> 6;
        int lane = lin & 63;
        int quad = lane >> 4, l15 = lane & 15;
        int f = nt * 16 + l15;
        bf16x8 vv;
        #pragma unroll
        for (int j = 0; j < 8; j++) vv[j] = S[quad * 8 + j][f];
        *(bf16x8*)(WeTp + (size_t)e * 16384 +
                   ((size_t)(nt * 4 + qd) * 64 + lane) * 8) = vv;   // coalesced
    }
}

// ---------------------------------------------------------------------------
// Load one expert's B fragments (2 n-tiles x 4 k-steps) from packed WeTp.
// Each load: lane-consecutive 16B -> one 1KB coalesced transaction.
// ---------------------------------------------------------------------------
__device__ __forceinline__ void loadBp(
    bf16x8 (&dst)[2][4], const __bf16* __restrict__ WeTp,
    int e, int wid, int lane)
{
    const __bf16* b = WeTp + (size_t)e * 16384 + (size_t)lane * 8;
    #pragma unroll
    for (int t2 = 0; t2 < 2; t2++)
        #pragma unroll
        for (int s = 0; s < 4; s++)
            dst[t2][s] = *(const bf16x8*)(b + ((wid * 2 + t2) * 4 + s) * 512);
}

// ---------------------------------------------------------------------------
// K1: FUSED gate + expert. 64 tokens/block.
// Entry: stage x fp32 + gate weights (coalesced). Gate fp64 dots fed from
// LDS (q-outer, W-hoisted; R0 op order -> bit-identical top-k) -> top-3 ->
// comb -> dense MFMA expert loop (register-resident, packed coalesced B)
// -> bias epilogue -> coalesced store (two 32-row halves).
// Importance: LDS partials -> one global atomicAdd per expert per block
// (imp_g zeroed by k_prep, stream-ordered).
// LDS (~59.4K, 2 blocks/CU; occupancy is register-pinned at 2 waves/SIMD):
//   union u: xs fp32 [64][132] (33.8K, entry..X2) | yh f32 (16.9K, X4)
//   union v: WgT+WnT (16.9K, dead after G2) | beS+combT (12.5K, G5..X4)
//   ga fp64 [64][17] dedicated (8.7K, G2..G4)
// MFMA 16x16x32 layouts (m89-verified):
//   A: lane l holds A[m=l&15][k=(l>>4)*8+j]; D: col=l&15, row=(l>>4)*4+reg
// ---------------------------------------------------------------------------
__global__ __launch_bounds__(256, 2) void k_fused(
    const float* __restrict__ x, const float* __restrict__ noise,
    const float* __restrict__ Wg, const float* __restrict__ bg,
    const float* __restrict__ Wn, const float* __restrict__ bn,
    const __bf16* __restrict__ WeTp, const float* __restrict__ be,
    float* __restrict__ out, float* __restrict__ imp_g)
{
    __shared__ union {
        float xs[TPB][DD + 4];                                         // 33.8K
        float yh[32][DD + 4];                                          // 16.9K
    } u;
    __shared__ union {
        struct { float WgT[NE][DD + 4]; float WnT[NE][DD + 4]; } w;    // 16.9K
        struct { float beS[NE][DD]; float combT[NE][TPB + 4]; } p;     // 12.5K
    } v;
    __shared__ double ga[TPB][NE + 1];                                 // 8.7K
    __shared__ float tkw[TPB][NK];
    __shared__ int   tke[TPB][NK];
    __shared__ float impS[NE];

    const int tid  = threadIdx.x;
    const int n0   = blockIdx.x * TPB;
    const int lane = tid & 63;
    const int wid  = tid >> 6;             // wave -> cols wid*32..+31
    const int l15  = lane & 15;
    const int quad = lane >> 4;
    const int e16  = tid & 15;             // gate-phase expert id
    const int tl   = tid >> 4;             // gate-phase token lane

    // ---- G1: stage x fp32 (single global read) + gate weights; zero impS ----
    if (tid < NE) impS[tid] = 0.0f;
    for (int i = tid; i < DD * NE; i += 256) {
        int d = i >> 4, ee = i & 15;
        v.w.WgT[ee][d] = Wg[i];
        v.w.WnT[ee][d] = Wn[i];
    }
    for (int idx = tid; idx < TPB * DD / 4; idx += 256) {   // coalesced float4
        int t = idx >> 5, q = idx & 31;
        *(f32x4*)&u.xs[t][q * 4] =
            *(const f32x4*)(x + (size_t)(n0 + t) * DD + q * 4);
    }
    __syncthreads();

    // ---- G2+G3: fp64 dots, q-outer, fed from LDS ----
    // Per-chain fp64 op order identical to R0: chain j accumulates
    // x[4q+j]*w[4q+j] in ascending q; final (g0+g1)+(g2+g3); exact f32->f64
    // converts -> bit-identical gate values, identical top-k.
    {
        const f32x4* wgp = (const f32x4*)&v.w.WgT[e16][0];
        const f32x4* wnp = (const f32x4*)&v.w.WnT[e16][0];

        double Ga[4][4], Ha[4][4];
        #pragma unroll
        for (int g = 0; g < 4; g++)
            #pragma unroll
            for (int j = 0; j < 4; j++) { Ga[g][j] = 0.0; Ha[g][j] = 0.0; }

        #pragma unroll 2
        for (int q = 0; q < DD / 4; q++) {
            f32x4 wg = wgp[q], wn = wnp[q];
            double wg0 = (double)wg[0], wg1 = (double)wg[1];
            double wg2 = (double)wg[2], wg3 = (double)wg[3];
            double wn0 = (double)wn[0], wn1 = (double)wn[1];
            double wn2 = (double)wn[2], wn3 = (double)wn[3];
            f32x4 xv[4];
            #pragma unroll
            for (int g = 0; g < 4; g++)
                xv[g] = *(const f32x4*)&u.xs[g * 16 + tl][q * 4];
            #pragma unroll
            for (int g = 0; g < 4; g++) {
                double x0 = (double)xv[g][0], x1 = (double)xv[g][1];
                double x2 = (double)xv[g][2], x3 = (double)xv[g][3];
                Ga[g][0] += x0 * wg0; Ga[g][1] += x1 * wg1;
                Ga[g][2] += x2 * wg2; Ga[g][3] += x3 * wg3;
                Ha[g][0] += x0 * wn0; Ha[g][1] += x1 * wn1;
                Ha[g][2] += x2 * wn2; Ha[g][3] += x3 * wn3;
            }
        }

        const double bge = (double)bg[e16], bne = (double)bn[e16];
        #pragma unroll
        for (int g = 0; g < 4; g++) {
            int t = g * 16 + tl;
            double gsum = (Ga[g][0] + Ga[g][1]) + (Ga[g][2] + Ga[g][3]);
            double hsum = (Ha[g][0] + Ha[g][1]) + (Ha[g][2] + Ha[g][3]);
            double nz = (double)noise[(size_t)(n0 + t) * NE + e16];
            ga[t][e16] = gsum + bge + nz * softplus_d(hsum + bne);
        }
    }
    __syncthreads();

    // ---- G4: top-3 + softmax (64 threads) ----
    if (tid < TPB) {
        int t = tid;
        double vk[NK]; int ix[NK];
        unsigned taken = 0;
        for (int k = 0; k < NK; k++) {
            double best = -INFINITY; int bi = 0;
            for (int j = 0; j < NE; j++) {
                if (!((taken >> j) & 1u)) {
                    double gv = ga[t][j];
                    if (gv > best) { best = gv; bi = j; }  // strict >: low idx tie
                }
            }
            taken |= 1u << bi;
            vk[k] = best; ix[k] = bi;
        }
        double e1 = exp(vk[1] - vk[0]);
        double e2 = exp(vk[2] - vk[0]);
        double inv = 1.0 / (1.0 + e1 + e2);
        tke[t][0] = ix[0]; tke[t][1] = ix[1]; tke[t][2] = ix[2];
        tkw[t][0] = (float)inv;
        tkw[t][1] = (float)(e1 * inv);
        tkw[t][2] = (float)(e2 * inv);
    }
    __syncthreads();   // W (v.w) dead since G2 -> v.p reusable now

    // ---- G5: comb (global + LDS combT), impS, beS staging ----
    for (int g = 0; g < 4; g++) {
        int t = g * 16 + tl;
        float c = 0.f;
        if (tke[t][0] == e16) c = tkw[t][0];
        if (tke[t][1] == e16) c = tkw[t][1];
        if (tke[t][2] == e16) c = tkw[t][2];
        out[OUT_COMB + (size_t)(n0 + t) * NE + e16] = c;
        v.p.combT[e16][t] = c;
        if (c != 0.f) atomicAdd(&impS[e16], c);
    }
    for (int idx = tid; idx < NE * DD; idx += 256)      // stage be
        v.p.beS[idx >> 7][idx & 127] = be[idx];
    __syncthreads();

    // importance partials -> global (device-scope atomics)
    if (tid < NE) atomicAdd(&imp_g[tid], impS[tid]);

    // ---- X2: build bf16 A fragments from fp32 xs (read LDS once) ----
    // Same (__bf16) converts as the old restage path -> identical values.
    bf16x8 Af[4][4];
    #pragma unroll
    for (int a = 0; a < 4; a++)
        #pragma unroll
        for (int s = 0; s < 4; s++) {
            const float* src = &u.xs[a * 16 + l15][32 * s + quad * 8];
            f32x4 lo = *(const f32x4*)src;
            f32x4 hi = *(const f32x4*)(src + 4);
            bf16x8 vv;
            vv[0] = (__bf16)lo[0]; vv[1] = (__bf16)lo[1];
            vv[2] = (__bf16)lo[2]; vv[3] = (__bf16)lo[3];
            vv[4] = (__bf16)hi[0]; vv[5] = (__bf16)hi[1];
            vv[6] = (__bf16)hi[2]; vv[7] = (__bf16)hi[3];
            Af[a][s] = vv;
        }

    // ---- X3: expert loop, register-resident, dbuf coalesced B ----
    f32x4 logits[4][2];
    #pragma unroll
    for (int a = 0; a < 4; a++) {
        logits[a][0] = (f32x4){0.f, 0.f, 0.f, 0.f};
        logits[a][1] = (f32x4){0.f, 0.f, 0.f, 0.f};
    }
    bf16x8 Bf[2][2][4];
    loadBp(Bf[0], WeTp, 0, wid, lane);

    #pragma unroll 2
    for (int e = 0; e < NE; e++) {
        const int cur = e & 1;
        if (e + 1 < NE) loadBp(Bf[cur ^ 1], WeTp, e + 1, wid, lane);

        f32x4 acc[4][2];
        #pragma unroll
        for (int a = 0; a < 4; a++) {
            acc[a][0] = (f32x4){0.f, 0.f, 0.f, 0.f};
            acc[a][1] = (f32x4){0.f, 0.f, 0.f, 0.f};
        }
        #pragma unroll
        for (int s = 0; s < 4; s++)        // s-outer: 8 indep chains
            #pragma unroll
            for (int a = 0; a < 4; a++) {
                acc[a][0] = __builtin_amdgcn_mfma_f32_16x16x32_bf16(
                    Af[a][s], Bf[cur][0][s], acc[a][0], 0, 0, 0);
                acc[a][1] = __builtin_amdgcn_mfma_f32_16x16x32_bf16(
                    Af[a][s], Bf[cur][1][s], acc[a][1], 0, 0, 0);
            }
        #pragma unroll
        for (int a = 0; a < 4; a++) {
            f32x4 cv = *(const f32x4*)&v.p.combT[e][a * 16 + quad * 4];
            #pragma unroll
            for (int r = 0; r < 4; r++) {
                logits[a][0][r] = fmaf(cv[r], acc[a][0][r], logits[a][0][r]);
                logits[a][1][r] = fmaf(cv[r], acc[a][1][r], logits[a][1][r]);
            }
        }
    }

    // ---- X4: bias epilogue + LDS-staged coalesced store (two halves) ----
    const int nA = wid * 32, nB = nA + 16;
    #pragma unroll 4
    for (int e = 0; e < NE; e++) {
        float bA = v.p.beS[e][nA + l15];
        float bB = v.p.beS[e][nB + l15];
        #pragma unroll
        for (int a = 0; a < 4; a++) {
            f32x4 cv = *(const f32x4*)&v.p.combT[e][a * 16 + quad * 4];
            #pragma unroll
            for (int r = 0; r < 4; r++) {
                logits[a][0][r] = fmaf(cv[r], bA, logits[a][0][r]);
                logits[a][1][r] = fmaf(cv[r], bB, logits[a][1][r]);
            }
        }
    }
    #pragma unroll
    for (int h = 0; h < 2; h++) {
        // h=0 barrier: ALL threads finished X2's xs reads (xs/yh union safe).
        __syncthreads();
        #pragma unroll
        for (int a2 = 0; a2 < 2; a2++) {
            const int a = h * 2 + a2;
            #pragma unroll
            for (int r = 0; r < 4; r++) {
                int row = a2 * 16 + quad * 4 + r;   // 0..31 within half
                u.yh[row][nA + l15] = logits[a][0][r];
                u.yh[row][nB + l15] = logits[a][1][r];
            }
        }
        __syncthreads();
        float4* op4 = (float4*)(out + ((size_t)n0 + h * 32) * DD);
        for (int idx = tid; idx < 32 * DD / 4; idx += 256) {
            int t = idx >> 5, q = idx & 31;
            op4[idx] = *(const float4*)&u.yh[t][q * 4];
        }
    }
}

// ---------------------------------------------------------------------------
// K2: loss from 16 globally-accumulated importances (atomic sums from k_fused).
// ---------------------------------------------------------------------------
__global__ __launch_bounds__(64) void k_loss(
    const float* __restrict__ imp_g, float* __restrict__ out)
{
    if (threadIdx.x == 0) {
        double mean = 0.0;
        for (int i = 0; i < NE; i++) mean += (double)imp_g[i];
        mean /= NE;
        double var = 0.0;
        for (int i = 0; i < NE; i++) {
            double d = (double)imp_g[i] - mean; var += d * d;
        }
        var /= (NE - 1);                    // ddof=1
        out[OUT_LOSS] = (float)(var / (mean * mean));
    }
}

// ---------------------------------------------------------------------------
extern "C" void kernel_launch(void* const* d_in, const int* in_sizes, int n_in,
                              void* d_out, int out_size, void* d_ws, size_t ws_size,
                              hipStream_t stream)
{
    (void)in_sizes; (void)n_in; (void)out_size; (void)ws_size;
    const float* x     = (const float*)d_in[0];
    const float* noise = (const float*)d_in[1];
    const float* Wg    = (const float*)d_in[2];
    const float* bg    = (const float*)d_in[3];
    const float* Wn    = (const float*)d_in[4];
    const float* bn    = (const float*)d_in[5];
    const float* We    = (const float*)d_in[6];
    const float* be    = (const float*)d_in[7];
    float* out = (float*)d_out;

    char*   ws    = (char*)d_ws;
    float*  imp_g = (float*)ws;                  // 64 B (16 floats)
    __bf16* WeTp  = (__bf16*)(ws + 1024);        // 512 KB, 16B-aligned

    hipLaunchKernelGGL(k_prep, dim3(64), dim3(256), 0, stream,
                       We, WeTp, imp_g);
    hipLaunchKernelGGL(k_fused, dim3(NBLK), dim3(256), 0, stream,
                       x, noise, Wg, bg, Wn, bn, WeTp, be, out, imp_g);
    hipLaunchKernelGGL(k_loss, dim3(1), dim3(64), 0, stream, imp_g, out);
}

// Round 12
// 155.622 us; speedup vs baseline: 1.3435x; 1.0057x over previous
//
#include <hip/hip_runtime.h>
#include <math.h>

// SparseMOELayer: N=65536 tokens, D=128, E=16 experts, top-3 routing.
// Outputs concat: logits[N*D] | importance_loss[1] | comb[N*E]
//
// R12 = R11 (= R6, measured optimum) + ONE counter-driven fix:
//   G2 token remap t = tl*4+g (was g*16+tl). Old pattern read rows
//   {tl,tl+16,tl+32,tl+48}: inter-row stride 16*132 floats == 0 mod 32
//   banks -> 4 addresses on ONE bank -> 4-way conflict (1.58x, m136) on
//   all 128 ds_read_b128/thread in G2 (the 2.26M SQ_LDS_BANK_CONFLICT).
//   New rows {16w+g+0,4,8,12}: banks {b,b+16}x2 -> free 2-way minimum.
//   Same chains, same op order, same ga[t][e16] dest -> bit-identical.
// Falsification record (measured on MI355X):
//  R1:  launch_bounds(256,4): unified VGPR+AGPR cap 128 < ~190 -> 1GB spill.
//  R3:  fp64 W in LDS -> G2 LDS-BW-bound; per-block threadfence ticket ->
//       L2 drain stalls.
//  R5:  LDS 52.7K->35.9K: occupancy flat -> LDS not binding.
//  R7:  512-thr reg-diet: occ 19->39%, dur WORSE -> not wave-starved.
//  R8:  kernel split: phases serialize globally -> worse.
//  R9/R10: gate-under-expert jam: neutral-to-worse; non-LDS-staged stores
//       cost +21MB write amplification.
#define NTOK 65536
#define DD   128
#define NE   16
#define NK   3
#define TPB  64                    // tokens per block
#define NBLK (NTOK / TPB)          // 1024

#define OUT_LOSS ((size_t)NTOK * DD)
#define OUT_COMB ((size_t)NTOK * DD + 1)

typedef __bf16 bf16x8 __attribute__((ext_vector_type(8)));
typedef float  f32x4  __attribute__((ext_vector_type(4)));

__device__ __forceinline__ double softplus_d(double z) {
    return fmax(z, 0.0) + log1p(exp(-fabs(z)));
}

// ---------------------------------------------------------------------------
// K0: pack We[e][d][f] fp32 -> WeTp bf16, FRAGMENT-MAJOR:
//   WeTp[e][nt][s][lane][j]  (flat: e*16384 + (nt*4+s)*512 + lane*8 + j)
//   holds We[d = s*32 + (lane>>4)*8 + j][f = nt*16 + (lane&15)].
// Consumer loadBp then reads one bf16x8/lane at consecutive 16B -> each
// B-frag load is ONE coalesced 1KB transaction.
// 64 blocks: (expert e = blk>>2, k-step s = blk&3). Block 0 zeroes imp_g.
// ---------------------------------------------------------------------------
__global__ __launch_bounds__(256) void k_prep(
    const float* __restrict__ We, __bf16* __restrict__ WeTp,
    float* __restrict__ imp_g)
{
    __shared__ __bf16 S[32][DD + 8];
    const int tid = threadIdx.x;
    const int e  = blockIdx.x >> 2;
    const int qd = blockIdx.x & 3;             // == k-step s
    if (blockIdx.x == 0 && tid < NE) imp_g[tid] = 0.f;
    const size_t base = (size_t)e * DD * DD + (size_t)qd * 32 * DD;
    for (int i = tid; i < 32 * DD; i += 256) { // coalesced read, d-quarter
        int dd = i >> 7, f = i & 127;
        S[dd][f] = (__bf16)We[base + i];
    }
    __syncthreads();
    #pragma unroll
    for (int it = 0; it < 2; it++) {
        int lin  = it * 256 + tid;             // 0..511 vectors
        int nt   = lin >> 6;
        int lane = lin & 63;
        int quad = lane >> 4, l15 = lane & 15;
        int f = nt * 16 + l15;
        bf16x8 vv;
        #pragma unroll
        for (int j = 0; j < 8; j++) vv[j] = S[quad * 8 + j][f];
        *(bf16x8*)(WeTp + (size_t)e * 16384 +
                   ((size_t)(nt * 4 + qd) * 64 + lane) * 8) = vv;   // coalesced
    }
}

// ---------------------------------------------------------------------------
// Load one expert's B fragments (2 n-tiles x 4 k-steps) from packed WeTp.
// Each load: lane-consecutive 16B -> one 1KB coalesced transaction.
// ---------------------------------------------------------------------------
__device__ __forceinline__ void loadBp(
    bf16x8 (&dst)[2][4], const __bf16* __restrict__ WeTp,
    int e, int wid, int lane)
{
    const __bf16* b = WeTp + (size_t)e * 16384 + (size_t)lane * 8;
    #pragma unroll
    for (int t2 = 0; t2 < 2; t2++)
        #pragma unroll
        for (int s = 0; s < 4; s++)
            dst[t2][s] = *(const bf16x8*)(b + ((wid * 2 + t2) * 4 + s) * 512);
}

// ---------------------------------------------------------------------------
// K1: FUSED gate + expert. 64 tokens/block.
// Entry: stage x fp32 + gate weights (coalesced). Gate fp64 dots fed from
// LDS (q-outer, W-hoisted, conflict-free token map; R0 op order ->
// bit-identical top-k) -> top-3 -> comb -> dense MFMA expert loop
// (register-resident, packed coalesced B) -> bias epilogue -> coalesced
// store (two 32-row halves).
// Importance: LDS partials -> one global atomicAdd per expert per block
// (imp_g zeroed by k_prep, stream-ordered).
// LDS (~59.4K, 2 blocks/CU; occupancy is register-pinned at 2 waves/SIMD):
//   union u: xs fp32 [64][132] (33.8K, entry..X2) | yh f32 (16.9K, X4)
//   union v: WgT+WnT (16.9K, dead after G2) | beS+combT (12.5K, G5..X4)
//   ga fp64 [64][17] dedicated (8.7K, G2..G4)
// MFMA 16x16x32 layouts (m89-verified):
//   A: lane l holds A[m=l&15][k=(l>>4)*8+j]; D: col=l&15, row=(l>>4)*4+reg
// ---------------------------------------------------------------------------
__global__ __launch_bounds__(256, 2) void k_fused(
    const float* __restrict__ x, const float* __restrict__ noise,
    const float* __restrict__ Wg, const float* __restrict__ bg,
    const float* __restrict__ Wn, const float* __restrict__ bn,
    const __bf16* __restrict__ WeTp, const float* __restrict__ be,
    float* __restrict__ out, float* __restrict__ imp_g)
{
    __shared__ union {
        float xs[TPB][DD + 4];                                         // 33.8K
        float yh[32][DD + 4];                                          // 16.9K
    } u;
    __shared__ union {
        struct { float WgT[NE][DD + 4]; float WnT[NE][DD + 4]; } w;    // 16.9K
        struct { float beS[NE][DD]; float combT[NE][TPB + 4]; } p;     // 12.5K
    } v;
    __shared__ double ga[TPB][NE + 1];                                 // 8.7K
    __shared__ float tkw[TPB][NK];
    __shared__ int   tke[TPB][NK];
    __shared__ float impS[NE];

    const int tid  = threadIdx.x;
    const int n0   = blockIdx.x * TPB;
    const int lane = tid & 63;
    const int wid  = tid >> 6;             // wave -> cols wid*32..+31
    const int l15  = lane & 15;
    const int quad = lane >> 4;
    const int e16  = tid & 15;             // gate-phase expert id
    const int tl   = tid >> 4;             // gate-phase token lane

    // ---- G1: stage x fp32 (single global read) + gate weights; zero impS ----
    if (tid < NE) impS[tid] = 0.0f;
    for (int i = tid; i < DD * NE; i += 256) {
        int d = i >> 4, ee = i & 15;
        v.w.WgT[ee][d] = Wg[i];
        v.w.WnT[ee][d] = Wn[i];
    }
    for (int idx = tid; idx < TPB * DD / 4; idx += 256) {   // coalesced float4
        int t = idx >> 5, q = idx & 31;
        *(f32x4*)&u.xs[t][q * 4] =
            *(const f32x4*)(x + (size_t)(n0 + t) * DD + q * 4);
    }
    __syncthreads();

    // ---- G2+G3: fp64 dots, q-outer, fed from LDS ----
    // Token map t = tl*4+g (R12): per-instruction rows {16w+g+0,4,8,12}
    // -> 2-way bank aliasing (free) instead of 4-way (old g*16+tl map).
    // Per-chain fp64 op order identical to R0: chain j accumulates
    // x[4q+j]*w[4q+j] in ascending q; final (g0+g1)+(g2+g3); exact f32->f64
    // converts -> bit-identical gate values, identical top-k.
    {
        const f32x4* wgp = (const f32x4*)&v.w.WgT[e16][0];
        const f32x4* wnp = (const f32x4*)&v.w.WnT[e16][0];

        double Ga[4][4], Ha[4][4];
        #pragma unroll
        for (int g = 0; g < 4; g++)
            #pragma unroll
            for (int j = 0; j < 4; j++) { Ga[g][j] = 0.0; Ha[g][j] = 0.0; }

        #pragma unroll 2
        for (int q = 0; q < DD / 4; q++) {
            f32x4 wg = wgp[q], wn = wnp[q];
            double wg0 = (double)wg[0], wg1 = (double)wg[1];
            double wg2 = (double)wg[2], wg3 = (double)wg[3];
            double wn0 = (double)wn[0], wn1 = (double)wn[1];
            double wn2 = (double)wn[2], wn3 = (double)wn[3];
            f32x4 xv[4];
            #pragma unroll
            for (int g = 0; g < 4; g++)
                xv[g] = *(const f32x4*)&u.xs[tl * 4 + g][q * 4];
            #pragma unroll
            for (int g = 0; g < 4; g++) {
                double x0 = (double)xv[g][0], x1 = (double)xv[g][1];
                double x2 = (double)xv[g][2], x3 = (double)xv[g][3];
                Ga[g][0] += x0 * wg0; Ga[g][1] += x1 * wg1;
                Ga[g][2] += x2 * wg2; Ga[g][3] += x3 * wg3;
                Ha[g][0] += x0 * wn0; Ha[g][1] += x1 * wn1;
                Ha[g][2] += x2 * wn2; Ha[g][3] += x3 * wn3;
            }
        }

        const double bge = (double)bg[e16], bne = (double)bn[e16];
        #pragma unroll
        for (int g = 0; g < 4; g++) {
            int t = tl * 4 + g;
            double gsum = (Ga[g][0] + Ga[g][1]) + (Ga[g][2] + Ga[g][3]);
            double hsum = (Ha[g][0] + Ha[g][1]) + (Ha[g][2] + Ha[g][3]);
            double nz = (double)noise[(size_t)(n0 + t) * NE + e16];
            ga[t][e16] = gsum + bge + nz * softplus_d(hsum + bne);
        }
    }
    __syncthreads();

    // ---- G4: top-3 + softmax (64 threads) ----
    if (tid < TPB) {
        int t = tid;
        double vk[NK]; int ix[NK];
        unsigned taken = 0;
        for (int k = 0; k < NK; k++) {
            double best = -INFINITY; int bi = 0;
            for (int j = 0; j < NE; j++) {
                if (!((taken >> j) & 1u)) {
                    double gv = ga[t][j];
                    if (gv > best) { best = gv; bi = j; }  // strict >: low idx tie
                }
            }
            taken |= 1u << bi;
            vk[k] = best; ix[k] = bi;
        }
        double e1 = exp(vk[1] - vk[0]);
        double e2 = exp(vk[2] - vk[0]);
        double inv = 1.0 / (1.0 + e1 + e2);
        tke[t][0] = ix[0]; tke[t][1] = ix[1]; tke[t][2] = ix[2];
        tkw[t][0] = (float)inv;
        tkw[t][1] = (float)(e1 * inv);
        tkw[t][2] = (float)(e2 * inv);
    }
    __syncthreads();   // W (v.w) dead since G2 -> v.p reusable now

    // ---- G5: comb (global + LDS combT), impS, beS staging ----
    for (int g = 0; g < 4; g++) {
        int t = g * 16 + tl;
        float c = 0.f;
        if (tke[t][0] == e16) c = tkw[t][0];
        if (tke[t][1] == e16) c = tkw[t][1];
        if (tke[t][2] == e16) c = tkw[t][2];
        out[OUT_COMB + (size_t)(n0 + t) * NE + e16] = c;
        v.p.combT[e16][t] = c;
        if (c != 0.f) atomicAdd(&impS[e16], c);
    }
    for (int idx = tid; idx < NE * DD; idx += 256)      // stage be
        v.p.beS[idx >> 7][idx & 127] = be[idx];
    __syncthreads();

    // importance partials -> global (device-scope atomics)
    if (tid < NE) atomicAdd(&imp_g[tid], impS[tid]);

    // ---- X2: build bf16 A fragments from fp32 xs (read LDS once) ----
    // Same (__bf16) converts as the old restage path -> identical values.
    bf16x8 Af[4][4];
    #pragma unroll
    for (int a = 0; a < 4; a++)
        #pragma unroll
        for (int s = 0; s < 4; s++) {
            const float* src = &u.xs[a * 16 + l15][32 * s + quad * 8];
            f32x4 lo = *(const f32x4*)src;
            f32x4 hi = *(const f32x4*)(src + 4);
            bf16x8 vv;
            vv[0] = (__bf16)lo[0]; vv[1] = (__bf16)lo[1];
            vv[2] = (__bf16)lo[2]; vv[3] = (__bf16)lo[3];
            vv[4] = (__bf16)hi[0]; vv[5] = (__bf16)hi[1];
            vv[6] = (__bf16)hi[2]; vv[7] = (__bf16)hi[3];
            Af[a][s] = vv;
        }

    // ---- X3: expert loop, register-resident, dbuf coalesced B ----
    f32x4 logits[4][2];
    #pragma unroll
    for (int a = 0; a < 4; a++) {
        logits[a][0] = (f32x4){0.f, 0.f, 0.f, 0.f};
        logits[a][1] = (f32x4){0.f, 0.f, 0.f, 0.f};
    }
    bf16x8 Bf[2][2][4];
    loadBp(Bf[0], WeTp, 0, wid, lane);

    #pragma unroll 2
    for (int e = 0; e < NE; e++) {
        const int cur = e & 1;
        if (e + 1 < NE) loadBp(Bf[cur ^ 1], WeTp, e + 1, wid, lane);

        f32x4 acc[4][2];
        #pragma unroll
        for (int a = 0; a < 4; a++) {
            acc[a][0] = (f32x4){0.f, 0.f, 0.f, 0.f};
            acc[a][1] = (f32x4){0.f, 0.f, 0.f, 0.f};
        }
        #pragma unroll
        for (int s = 0; s < 4; s++)        // s-outer: 8 indep chains
            #pragma unroll
            for (int a = 0; a < 4; a++) {
                acc[a][0] = __builtin_amdgcn_mfma_f32_16x16x32_bf16(
                    Af[a][s], Bf[cur][0][s], acc[a][0], 0, 0, 0);
                acc[a][1] = __builtin_amdgcn_mfma_f32_16x16x32_bf16(
                    Af[a][s], Bf[cur][1][s], acc[a][1], 0, 0, 0);
            }
        #pragma unroll
        for (int a = 0; a < 4; a++) {
            f32x4 cv = *(const f32x4*)&v.p.combT[e][a * 16 + quad * 4];
            #pragma unroll
            for (int r = 0; r < 4; r++) {
                logits[a][0][r] = fmaf(cv[r], acc[a][0][r], logits[a][0][r]);
                logits[a][1][r] = fmaf(cv[r], acc[a][1][r], logits[a][1][r]);
            }
        }
    }

    // ---- X4: bias epilogue + LDS-staged coalesced store (two halves) ----
    const int nA = wid * 32, nB = nA + 16;
    #pragma unroll 4
    for (int e = 0; e < NE; e++) {
        float bA = v.p.beS[e][nA + l15];
        float bB = v.p.beS[e][nB + l15];
        #pragma unroll
        for (int a = 0; a < 4; a++) {
            f32x4 cv = *(const f32x4*)&v.p.combT[e][a * 16 + quad * 4];
            #pragma unroll
            for (int r = 0; r < 4; r++) {
                logits[a][0][r] = fmaf(cv[r], bA, logits[a][0][r]);
                logits[a][1][r] = fmaf(cv[r], bB, logits[a][1][r]);
            }
        }
    }
    #pragma unroll
    for (int h = 0; h < 2; h++) {
        // h=0 barrier: ALL threads finished X2's xs reads (xs/yh union safe).
        __syncthreads();
        #pragma unroll
        for (int a2 = 0; a2 < 2; a2++) {
            const int a = h * 2 + a2;
            #pragma unroll
            for (int r = 0; r < 4; r++) {
                int row = a2 * 16 + quad * 4 + r;   // 0..31 within half
                u.yh[row][nA + l15] = logits[a][0][r];
                u.yh[row][nB + l15] = logits[a][1][r];
            }
        }
        __syncthreads();
        float4* op4 = (float4*)(out + ((size_t)n0 + h * 32) * DD);
        for (int idx = tid; idx < 32 * DD / 4; idx += 256) {
            int t = idx >> 5, q = idx & 31;
            op4[idx] = *(const float4*)&u.yh[t][q * 4];
        }
    }
}

// ---------------------------------------------------------------------------
// K2: loss from 16 globally-accumulated importances (atomic sums from k_fused).
// ---------------------------------------------------------------------------
__global__ __launch_bounds__(64) void k_loss(
    const float* __restrict__ imp_g, float* __restrict__ out)
{
    if (threadIdx.x == 0) {
        double mean = 0.0;
        for (int i = 0; i < NE; i++) mean += (double)imp_g[i];
        mean /= NE;
        double var = 0.0;
        for (int i = 0; i < NE; i++) {
            double d = (double)imp_g[i] - mean; var += d * d;
        }
        var /= (NE - 1);                    // ddof=1
        out[OUT_LOSS] = (float)(var / (mean * mean));
    }
}

// ---------------------------------------------------------------------------
extern "C" void kernel_launch(void* const* d_in, const int* in_sizes, int n_in,
                              void* d_out, int out_size, void* d_ws, size_t ws_size,
                              hipStream_t stream)
{
    (void)in_sizes; (void)n_in; (void)out_size; (void)ws_size;
    const float* x     = (const float*)d_in[0];
    const float* noise = (const float*)d_in[1];
    const float* Wg    = (const float*)d_in[2];
    const float* bg    = (const float*)d_in[3];
    const float* Wn    = (const float*)d_in[4];
    const float* bn    = (const float*)d_in[5];
    const float* We    = (const float*)d_in[6];
    const float* be    = (const float*)d_in[7];
    float* out = (float*)d_out;

    char*   ws    = (char*)d_ws;
    float*  imp_g = (float*)ws;                  // 64 B (16 floats)
    __bf16* WeTp  = (__bf16*)(ws + 1024);        // 512 KB, 16B-aligned

    hipLaunchKernelGGL(k_prep, dim3(64), dim3(256), 0, stream,
                       We, WeTp, imp_g);
    hipLaunchKernelGGL(k_fused, dim3(NBLK), dim3(256), 0, stream,
                       x, noise, Wg, bg, Wn, bn, WeTp, be, out, imp_g);
    hipLaunchKernelGGL(k_loss, dim3(1), dim3(64), 0, stream, imp_g, out);
}